// Round 8
// baseline (536.872 us; speedup 1.0000x reference)
//
#include <hip/hip_runtime.h>
#include <stdint.h>

#define PRE_K   6000
#define POST_K  1000
#define CAP     8192      // candidate buffer per batch
#define BINS    1024
#define ROWS    6016      // 94*64, padded row count for NMS
#define CH      94        // ROWS/64 chunks
#define JSPLIT  8         // k_rank comparison-range split
#define NEGF    -1000000000.0f
#define IOU_EPS 16.0f     // f32 decision margin; f32 abs error bound ~2
#define KREG    16        // far-OR pipeline slots (kept rows per chunk)

// ---- helpers ----------------------------------------------------------------

__device__ __forceinline__ uint32_t orderf(float f) {
  uint32_t u = __float_as_uint(f);
  return (u & 0x80000000u) ? ~u : (u | 0x80000000u);
}

__device__ __forceinline__ int score_bin(float sc) {
  int bin = (int)floorf((sc + 12.0f) * ((float)BINS / 24.0f));
  return bin < 0 ? 0 : (bin > BINS - 1 ? BINS - 1 : bin);
}

__device__ __forceinline__ int bin_slot(int bin) {
  return ((bin & 15) << 6) | (bin >> 4);
}

// full double-precision decode, matching the float64 numpy reference
__device__ __forceinline__ void decode_box(
    const float* __restrict__ anchors, const float* __restrict__ deltas,
    const int* __restrict__ isz, int n, int b,
    double& x1, double& y1, double& x2, double& y2, bool& valid) {
  double ax1 = (double)anchors[4 * n + 0], ay1 = (double)anchors[4 * n + 1];
  double ax2 = (double)anchors[4 * n + 2], ay2 = (double)anchors[4 * n + 3];
  double aw = ax2 - ax1, ah = ay2 - ay1;
  double acx = ax1 + 0.5 * aw, acy = ay1 + 0.5 * ah;
  double tx = (double)deltas[4 * n + 0], ty = (double)deltas[4 * n + 1];
  double tw = (double)deltas[4 * n + 2], th = (double)deltas[4 * n + 3];
  tw = tw < -10.0 ? -10.0 : (tw > 10.0 ? 10.0 : tw);
  th = th < -10.0 ? -10.0 : (th > 10.0 ? 10.0 : th);
  double px = acx + tx * aw, py = acy + ty * ah;
  double pw = aw * exp(tw), ph = ah * exp(th);
  double H = (double)isz[2 * b + 0], W = (double)isz[2 * b + 1];
  double wm = W - 1.0, hm = H - 1.0;
  x1 = px - 0.5 * pw; y1 = py - 0.5 * ph;
  x2 = px + 0.5 * pw; y2 = py + 0.5 * ph;
  x1 = fmin(fmax(x1, 0.0), wm); x2 = fmin(fmax(x2, 0.0), wm);
  y1 = fmin(fmax(y1, 0.0), hm); y2 = fmin(fmax(y2, 0.0), hm);
  valid = (x2 - x1 >= 16.0) && (y2 - y1 >= 16.0);
}

// exact f64 suppression test (symmetric in its two rows)
__device__ __forceinline__ bool iou_exact(const double* __restrict__ tbox,
                                          const double* __restrict__ tarea,
                                          size_t ri, size_t ci) {
  const double* pr = &tbox[ri * 4];
  const double* pc = &tbox[ci * 4];
  double w = fmin(pr[2], pc[2]) - fmax(pr[0], pc[0]); w = w > 0.0 ? w : 0.0;
  double h = fmin(pr[3], pc[3]) - fmax(pr[1], pc[1]); h = h > 0.0 ? h : 0.0;
  double it = w * h;
  return it > 0.7 * (tarea[ri] + tarea[ci] - it + 1e-9);
}

// ---- kernels ----------------------------------------------------------------

// Decode + validity + LDS-privatized histogram.
__global__ void __launch_bounds__(256) k_score(const float* __restrict__ anchors,
                                               const int* __restrict__ bix,
                                               const int* __restrict__ isz,
                                               const float* __restrict__ logits,
                                               const float* __restrict__ deltas,
                                               float* __restrict__ scores,
                                               uint32_t* __restrict__ hist, int N) {
  const int SPAN = 4096;
  int start = blockIdx.x * SPAN;
  int end = start + SPAN < N ? start + SPAN : N;
  __shared__ uint32_t lh[2][BINS];
  for (int i = threadIdx.x; i < 2 * BINS; i += 256) ((uint32_t*)lh)[i] = 0u;
  __shared__ int s_b0, s_b1;
  if (threadIdx.x == 0) { s_b0 = bix[start]; s_b1 = bix[end - 1]; }
  __syncthreads();
  int b0 = s_b0, b1 = s_b1;

  for (int n = start + (int)threadIdx.x; n < end; n += 256) {
    int b = bix[n];
    double x1, y1, x2, y2; bool valid;
    decode_box(anchors, deltas, isz, n, b, x1, y1, x2, y2, valid);
    float sc = valid ? logits[n] : NEGF;
    scores[n] = sc;
    if (valid) {
      int bin = score_bin(sc);
      if (b == b0)      atomicAdd(&lh[0][bin], 1u);
      else if (b == b1) atomicAdd(&lh[1][bin], 1u);
      else              atomicAdd(&hist[b * BINS + bin_slot(bin)], 1u);
    }
  }
  __syncthreads();
  for (int bin = threadIdx.x; bin < BINS; bin += 256) {
    uint32_t c0 = lh[0][bin];
    if (c0) atomicAdd(&hist[b0 * BINS + bin_slot(bin)], c0);
    if (b1 != b0) {
      uint32_t c1 = lh[1][bin];
      if (c1) atomicAdd(&hist[b1 * BINS + bin_slot(bin)], c1);
    }
  }
}

// Block-aggregated compaction with fused threshold scan.
__global__ void __launch_bounds__(1024) k_compact(const float* __restrict__ scores,
                                                  const int* __restrict__ bix,
                                                  const uint32_t* __restrict__ hist,
                                                  uint32_t* __restrict__ cnt,
                                                  uint64_t* __restrict__ cand, int N) {
  const int SPAN = 8192;
  int start = blockIdx.x * SPAN;
  int end = start + SPAN < N ? start + SPAN : N;
  int t = threadIdx.x;
  __shared__ int s_b0, s_b1;
  __shared__ uint32_t sh[BINS];
  __shared__ int s_bs;
  __shared__ uint32_t lcnt[8], lbase[8];
  if (t == 0) { s_b0 = bix[start]; s_b1 = bix[end - 1]; }
  if (t < 8) lcnt[t] = 0u;
  __syncthreads();
  int b0 = s_b0, b1 = s_b1;

  uint32_t bs0 = 0, bs1 = 0;
  for (int pass = 0; pass < 2; pass++) {
    int b = pass == 0 ? b0 : b1;
    if (pass == 1 && b1 == b0) { bs1 = bs0; break; }
    if (t < BINS) sh[t] = hist[b * BINS + bin_slot(t)];
    if (t == 0) s_bs = 0;
    __syncthreads();
    for (int off = 1; off < BINS; off <<= 1) {
      uint32_t v = (t < BINS && t + off < BINS) ? sh[t + off] : 0u;
      __syncthreads();
      if (t < BINS) sh[t] += v;
      __syncthreads();
    }
    if (t < BINS && sh[t] >= PRE_K) atomicMax(&s_bs, t);
    __syncthreads();
    if (pass == 0) bs0 = (uint32_t)s_bs; else bs1 = (uint32_t)s_bs;
    __syncthreads();
  }

  bool     predv[8];
  uint64_t keyv[8];
  uint32_t lposv[8];
  int      bv[8];
  int nt = 0;
  for (int base = start; base < end; base += 1024, nt++) {
    int n = base + t;
    bool pred = false; int b = 0; uint64_t key = 0ull; uint32_t lp = 0u;
    if (n < end) {
      float sc = scores[n];
      if (sc > 0.5f * NEGF) {
        b = bix[n];
        uint32_t bs = (b == b0) ? bs0 : bs1;
        if ((uint32_t)score_bin(sc) >= bs) {
          pred = true;
          key = ((uint64_t)orderf(sc) << 32) | (uint64_t)(uint32_t)(~(uint32_t)n);
          lp = atomicAdd(&lcnt[b], 1u);
        }
      }
    }
    predv[nt] = pred; keyv[nt] = key; lposv[nt] = lp; bv[nt] = b;
  }
  __syncthreads();
  if (t < 8) {
    uint32_t c = lcnt[t];
    lbase[t] = c ? atomicAdd(&cnt[t], c) : 0u;
  }
  __syncthreads();
  for (int k = 0; k < nt; k++) {
    if (predv[k]) {
      uint32_t pos = lbase[bv[k]] + lposv[k];
      if (pos < CAP) cand[(size_t)bv[k] * CAP + pos] = keyv[k];
    }
  }
}

// Partial rank-by-count; each (b,ic,js) block writes its partial rank slice.
__global__ void __launch_bounds__(256) k_rank(const uint64_t* __restrict__ cand,
                                              const uint32_t* __restrict__ cnt,
                                              uint32_t* __restrict__ prank) {
  int blk = blockIdx.x;
  int js = blk % JSPLIT;
  int ic = (blk / JSPLIT) % 32;
  int b  = blk / (JSPLIT * 32);
  int t = threadIdx.x;
  int C = (int)min(cnt[b], (uint32_t)CAP);
  if (ic * 256 >= C) return;
  const uint64_t* g = cand + (size_t)b * CAP;
  int i = ic * 256 + t;
  uint64_t ki = (i < C) ? g[i] : 0ull;

  int q = (C + JSPLIT - 1) / JSPLIT;
  int j0 = js * q;
  int j1 = j0 + q < C ? j0 + q : C;

  __shared__ uint64_t tile[1024];
  int rank = 0;
  for (int base = j0; base < j1; base += 1024) {
#pragma unroll
    for (int u = 0; u < 4; u++) {
      int j = base + u * 256 + t;
      tile[u * 256 + t] = (j < j1) ? g[j] : 0ull;
    }
    __syncthreads();
    int lim = j1 - base < 1024 ? j1 - base : 1024;
    const ulonglong2* t2 = (const ulonglong2*)tile;
    int pairs = lim >> 1;
    int jj = 0;
    for (; jj + 4 <= pairs; jj += 4) {
      ulonglong2 v0 = t2[jj + 0], v1 = t2[jj + 1];
      ulonglong2 v2 = t2[jj + 2], v3 = t2[jj + 3];
      rank += (v0.x > ki) ? 1 : 0; rank += (v0.y > ki) ? 1 : 0;
      rank += (v1.x > ki) ? 1 : 0; rank += (v1.y > ki) ? 1 : 0;
      rank += (v2.x > ki) ? 1 : 0; rank += (v2.y > ki) ? 1 : 0;
      rank += (v3.x > ki) ? 1 : 0; rank += (v3.y > ki) ? 1 : 0;
    }
    for (; jj < pairs; jj++) {
      ulonglong2 v = t2[jj];
      rank += (v.x > ki) ? 1 : 0; rank += (v.y > ki) ? 1 : 0;
    }
    if (lim & 1) rank += (tile[lim - 1] > ki) ? 1 : 0;
    __syncthreads();
  }
  if (i < C) prank[((size_t)b * JSPLIT + js) * CAP + i] = (uint32_t)rank;
}

// Fused place + gather: sums the JSPLIT partial ranks, then decodes the box
// directly into row=rank (f64 + f32 mirrors).
__global__ void __launch_bounds__(256) k_place_gather(
    const uint64_t* __restrict__ cand, const uint32_t* __restrict__ cnt,
    const uint32_t* __restrict__ prank,
    const float* __restrict__ anchors, const float* __restrict__ deltas,
    const int* __restrict__ isz,
    double* __restrict__ tbox, double* __restrict__ tarea,
    float4* __restrict__ tboxf, float* __restrict__ tareaf,
    int* __restrict__ top_n, int* __restrict__ Cnum, int B) {
  int idx = blockIdx.x * blockDim.x + threadIdx.x;
  if (idx >= B * CAP) return;
  int b = idx / CAP, i = idx % CAP;
  int C = (int)min(cnt[b], (uint32_t)CAP);
  if (i == 0) Cnum[b] = C < PRE_K ? C : PRE_K;
  if (i >= C) return;
  uint32_t rank = 0;
#pragma unroll
  for (int js = 0; js < JSPLIT; js++)
    rank += prank[((size_t)b * JSPLIT + js) * CAP + i];
  if (rank >= PRE_K) return;
  int n = (int)(~(uint32_t)(cand[idx] & 0xFFFFFFFFull));
  double x1, y1, x2, y2; bool valid;
  decode_box(anchors, deltas, isz, n, b, x1, y1, x2, y2, valid);
  size_t row = (size_t)b * ROWS + rank;
  tbox[row * 4 + 0] = x1;
  tbox[row * 4 + 1] = y1;
  tbox[row * 4 + 2] = x2;
  tbox[row * 4 + 3] = y2;
  double ar = (x2 - x1) * (y2 - y1);
  tarea[row] = ar;
  tboxf[row] = make_float4((float)x1, (float)y1, (float)x2, (float)y2);
  tareaf[row] = (float)ar;
  top_n[b * PRE_K + rank] = n;
}

// Suppression bit tiles, FULL upper triangle (rc <= cc), ballot-free:
// lane = ROW within the rc chunk; cols of the cc chunk broadcast from LDS.
// Chunk-major transposed layout: maskT[((b*CH + cc)*ROWS + row)*2 + w].
__global__ void __launch_bounds__(64) k_iou_mat(const float4* __restrict__ tboxf,
                                                const float* __restrict__ tareaf,
                                                const double* __restrict__ tbox,
                                                const double* __restrict__ tarea,
                                                const int* __restrict__ Cnum,
                                                uint32_t* __restrict__ maskT) {
  int rc = blockIdx.x;
  int cc = blockIdx.y;
  int b  = blockIdx.z;
  if (rc > cc) return;
  int C = Cnum[b];
  if (cc * 64 >= C) return;   // rc <= cc, so rc*64 < C too
  int lane = threadIdx.x;
  size_t bb = (size_t)b * ROWS;

  float4 rb4 = tboxf[bb + (size_t)rc * 64 + lane];
  float  sra = 0.7f * tareaf[bb + (size_t)rc * 64 + lane];
  __shared__ float4 cbx[64];
  __shared__ float  csa[64];
  cbx[lane] = tboxf[bb + (size_t)cc * 64 + lane];
  csa[lane] = 0.7f * tareaf[bb + (size_t)cc * 64 + lane];
  __syncthreads();

  bool isdiag = (rc == cc);
  uint32_t res0 = 0u, res1 = 0u;

  for (int j = 0; j < 64; j++) {
    float4 c4 = cbx[j];
    float sca = csa[j];
    float iw = fminf(c4.z, rb4.z) - fmaxf(c4.x, rb4.x);
    float ih = fminf(c4.w, rb4.w) - fmaxf(c4.y, rb4.y);
    iw = fmaxf(iw, 0.0f); ih = fmaxf(ih, 0.0f);
    float inter = iw * ih;
    float diff = fmaf(1.7f, inter, -(sra + sca));
    bool gt = isdiag ? (j > lane) : true;
    bool sup = gt && (diff > IOU_EPS);
    if (gt && !sup && diff > -IOU_EPS) {
      sup = iou_exact(tbox, tarea, bb + (size_t)rc * 64 + lane,
                      bb + (size_t)cc * 64 + j);
    }
    if (sup) { if (j < 32) res0 |= 1u << j; else res1 |= 1u << (j & 31); }
  }
  uint2* seg = (uint2*)(maskT + (((size_t)b * CH + cc) * ROWS + (size_t)rc * 64) * 2);
  seg[lane] = make_uint2(res0, res1);
}

// Greedy resolve, SINGLE-WAVE: wave 0 runs the whole chunk loop with zero
// barriers; all loop-carried state is wave-uniform in registers. Waves 1-3
// wait at one final __syncthreads and join for the output tail.
// acc[cc] = OR over already-kept rows j of mask(j, cc).
// Coverage of a row kept at chunk k:
//   cc = k+1, k+2 : shfl_xor ballot of prefetched pf/qf words at iter k
//   cc >= k+3     : lane-per-column loads issued at k (lz ping-pong regs,
//                   no integer division), committed via LDS atomicOr at k+2
//                   (~2 iterations of vmcnt slack, nothing drains it)
// acc[c+1] is ds_read-prefetched at the end of iteration c (per-wave LDS
// ordering makes this safe after the lane0 atomicOr).
__global__ void __launch_bounds__(256) k_nms_reduce(const uint32_t* __restrict__ maskT,
                                                    const double* __restrict__ tbox,
                                                    const int* __restrict__ Cnum,
                                                    const int* __restrict__ top_n,
                                                    const float* __restrict__ logits,
                                                    const float* __restrict__ deltas,
                                                    float* __restrict__ out, int B) {
  int b = blockIdx.x, t = threadIdx.x;
  int wave = t >> 6, lane = t & 63;
  int C = Cnum[b];
  int nch = (C + 63) >> 6;
  const uint2* Mb = (const uint2*)(maskT + (size_t)b * CH * ROWS * 2);
  size_t bb = (size_t)b * ROWS;

  __shared__ uint32_t acc[CH][2];      // forward-accumulated suppression bits
  __shared__ uint16_t kept[POST_K];    // kept rows, greedy order
  __shared__ uint16_t pend[64];        // rows kept at the current chunk
  __shared__ int      s_nkept;

  for (int i = t; i < CH * 2; i += 256) ((uint32_t*)acc)[i] = 0u;
  if (t == 0) s_nkept = 0;
  __syncthreads();

  if (wave == 0 && nch > 0) {
    const uint2 z2 = make_uint2(0u, 0u);
    // depth-2 prefetch register sets (parity: A = even chunks, B = odd).
    // For chunk c (rows base=c*64): dg = col c (diag), pf = col c+1, qf = c+2.
    uint2 dgA = Mb[(size_t)0 * ROWS + lane];
    uint2 pfA = (nch > 1) ? Mb[(size_t)1 * ROWS + lane] : z2;
    uint2 qfA = (nch > 2) ? Mb[(size_t)2 * ROWS + lane] : z2;
    uint2 dgB = (nch > 1) ? Mb[(size_t)1 * ROWS + 64 + lane] : z2;
    uint2 pfB = (nch > 2) ? Mb[(size_t)2 * ROWS + 64 + lane] : z2;
    uint2 qfB = (nch > 3) ? Mb[(size_t)3 * ROWS + 64 + lane] : z2;

    // far-OR ping-pong sets: issued at parity p, committed 2 iterations later
    uint2 lzA[KREG], lzB[KREG];
#pragma unroll
    for (int u = 0; u < KREG; u++) { lzA[u] = z2; lzB[u] = z2; }
    int nA = 0, ccA = 0, spA = 0;
    int nB = 0, ccB = 0, spB = 0;

    uint32_t pa0 = 0u, pa1 = 0u;   // prefetched acc[c] (acc[0] is zero)
    int nkept = 0;

    for (int c = 0; c < nch; c++) {
      // ---- (1) COMMIT far set (parity c), issued at c-2, targets cc >= c+1 --
      if (c & 1) {
        if (nB > 0) {
#pragma unroll
          for (int u = 0; u < KREG; u++) {
            if (u < nB && lane < spB) {
              if (lzB[u].x) atomicOr(&acc[ccB + lane][0], lzB[u].x);
              if (lzB[u].y) atomicOr(&acc[ccB + lane][1], lzB[u].y);
            }
          }
        }
      } else {
        if (nA > 0) {
#pragma unroll
          for (int u = 0; u < KREG; u++) {
            if (u < nA && lane < spA) {
              if (lzA[u].x) atomicOr(&acc[ccA + lane][0], lzA[u].x);
              if (lzA[u].y) atomicOr(&acc[ccA + lane][1], lzA[u].y);
            }
          }
        }
      }

      // ---- (2) RESOLVE chunk c using prefetched acc + diag words ----
      uint2 dgv, pfv, qfv;
      if (c & 1) { dgv = dgB; pfv = pfB; qfv = qfB; }
      else       { dgv = dgA; pfv = pfA; qfv = qfA; }
      int base = c << 6;
      uint64_t sup = (uint64_t)pa0 | ((uint64_t)pa1 << 32);
      int rem = C - base;
      if (rem < 64) sup |= ~((1ull << rem) - 1ull);
      uint64_t diag = (uint64_t)dgv.x | ((uint64_t)dgv.y << 32);
      uint64_t keptMask = 0ull;
      uint64_t alive = ~sup;
      uint64_t m = alive;
      while (m) {
        int i = __builtin_ctzll(m);
        keptMask |= 1ull << i;
        uint64_t d = (uint64_t)__shfl((long long)diag, i, 64);
        sup |= d | (1ull << i);
        m = alive & ~sup;
      }
      int allowed = POST_K - nkept;
      int pc2 = __popcll(keptMask);
      while (pc2 > allowed) {
        keptMask &= ~(1ull << (63 - __builtin_clzll(keptMask)));
        pc2--;
      }
      bool mine = (keptMask >> lane) & 1ull;
      if (mine) {
        int pfx = __popcll(keptMask & ((1ull << lane) - 1ull));
        kept[nkept + pfx] = (uint16_t)(base + lane);
        pend[pfx] = (uint16_t)(base + lane);
      }
      nkept += pc2;

      // ---- (3) near-diag ORs: kept rows of c -> acc[c+1], acc[c+2] ----
      if (c + 1 < nch && keptMask) {
        uint32_t v0 = mine ? pfv.x : 0u, v1 = mine ? pfv.y : 0u;
        uint32_t w0 = mine ? qfv.x : 0u, w1 = mine ? qfv.y : 0u;
#pragma unroll
        for (int off = 32; off > 0; off >>= 1) {
          v0 |= (uint32_t)__shfl_xor((int)v0, off, 64);
          v1 |= (uint32_t)__shfl_xor((int)v1, off, 64);
          w0 |= (uint32_t)__shfl_xor((int)w0, off, 64);
          w1 |= (uint32_t)__shfl_xor((int)w1, off, 64);
        }
        if (lane == 0) {
          if (v0) atomicOr(&acc[c + 1][0], v0);
          if (v1) atomicOr(&acc[c + 1][1], v1);
          if (c + 2 < nch) {
            if (w0) atomicOr(&acc[c + 2][0], w0);
            if (w1) atomicOr(&acc[c + 2][1], w1);
          }
        }
      }

      // ---- (4) issue depth-2 dg/pf/qf prefetch for chunk c+2 ----
      if (c + 2 < nch) {
        int cn = c + 2;
        int nb = cn << 6;
        uint2 d2 = Mb[(size_t)cn * ROWS + nb + lane];
        uint2 p2 = (cn + 1 < nch) ? Mb[(size_t)(cn + 1) * ROWS + nb + lane] : z2;
        uint2 q2 = (cn + 2 < nch) ? Mb[(size_t)(cn + 2) * ROWS + nb + lane] : z2;
        if (c & 1) { dgB = d2; pfB = p2; qfB = q2; }
        else       { dgA = d2; pfA = p2; qfA = q2; }
      }

      // ---- (5) issue far loads for rows kept at c (cc >= c+3, lane = col) --
      {
        int cc0 = c + 3;
        int span = nch - cc0;
        if (span < 0) span = 0;
        int npi = (span > 0) ? pc2 : 0;
        int rowv = (npi > 0) ? (int)pend[lane] : 0;
        int cap = npi < KREG ? npi : KREG;
        if (c & 1) {
#pragma unroll
          for (int u = 0; u < KREG; u++) {
            uint2 v = z2;
            if (u < cap) {
              int row = __shfl(rowv, u, 64);
              if (lane < span) v = Mb[(size_t)(cc0 + lane) * ROWS + row];
            }
            lzB[u] = v;
          }
          nB = cap; ccB = cc0; spB = span;
        } else {
#pragma unroll
          for (int u = 0; u < KREG; u++) {
            uint2 v = z2;
            if (u < cap) {
              int row = __shfl(rowv, u, 64);
              if (lane < span) v = Mb[(size_t)(cc0 + lane) * ROWS + row];
            }
            lzA[u] = v;
          }
          nA = cap; ccA = cc0; spA = span;
        }
        // overflow: immediate load + commit (targets cc >= c+3, read later)
        for (int u = KREG; u < npi; u++) {
          int row = __shfl(rowv, u, 64);
          if (lane < span) {
            uint2 v = Mb[(size_t)(cc0 + lane) * ROWS + row];
            if (v.x) atomicOr(&acc[cc0 + lane][0], v.x);
            if (v.y) atomicOr(&acc[cc0 + lane][1], v.y);
          }
        }
      }

      // ---- (6) prefetch acc[c+1] (per-wave LDS ordering after atomics) ----
      pa0 = 0u; pa1 = 0u;
      if (c + 1 < nch) { pa0 = acc[c + 1][0]; pa1 = acc[c + 1][1]; }

      if (nkept >= POST_K) break;
    }
    if (lane == 0) s_nkept = nkept;
  }
  __syncthreads();

  // ---- fused output: all 4 waves write this batch's POST_K rows ----
  int nkept = s_nkept;
  int M_out = B * POST_K;
  for (int s2 = t; s2 < POST_K; s2 += 256) {
    float p0 = 0.f, p1 = 0.f, p2 = 0.f, p3 = 0.f;
    float ob = 0.f, d0f = 0.f, d1f = 0.f, d2f = 0.f, d3f = 0.f;
    float bi = -1.0f, okv = 0.0f;
    if (s2 < nkept) {
      int j = (int)kept[s2];
      int n = top_n[b * PRE_K + j];
      const double* p = &tbox[(bb + j) * 4];
      p0 = (float)p[0]; p1 = (float)p[1]; p2 = (float)p[2]; p3 = (float)p[3];
      ob = logits[n];
      d0f = deltas[4 * n + 0]; d1f = deltas[4 * n + 1];
      d2f = deltas[4 * n + 2]; d3f = deltas[4 * n + 3];
      bi = (float)b; okv = 1.0f;
    }
    int idx = b * POST_K + s2;
    out[idx * 4 + 0] = p0;
    out[idx * 4 + 1] = p1;
    out[idx * 4 + 2] = p2;
    out[idx * 4 + 3] = p3;
    out[4 * M_out + idx] = bi;
    out[5 * M_out + idx] = ob;
    out[6 * M_out + idx * 4 + 0] = d0f;
    out[6 * M_out + idx * 4 + 1] = d1f;
    out[6 * M_out + idx * 4 + 2] = d2f;
    out[6 * M_out + idx * 4 + 3] = d3f;
    out[10 * M_out + idx] = okv;
  }
}

// ---- launch -----------------------------------------------------------------

extern "C" void kernel_launch(void* const* d_in, const int* in_sizes, int n_in,
                              void* d_out, int out_size, void* d_ws, size_t ws_size,
                              hipStream_t stream) {
  const float* anchors = (const float*)d_in[0];
  const int*   bix     = (const int*)d_in[1];
  const int*   isz     = (const int*)d_in[2];
  const float* logits  = (const float*)d_in[3];
  const float* deltas  = (const float*)d_in[4];
  float* out = (float*)d_out;

  int N = in_sizes[1];
  int B = in_sizes[2] / 2;

  uintptr_t p = (uintptr_t)d_ws;
  double*   tbox   = (double*)p;    p += (size_t)B * ROWS * 4 * sizeof(double);
  double*   tarea  = (double*)p;    p += (size_t)B * ROWS * sizeof(double);
  uint64_t* cand   = (uint64_t*)p;  p += (size_t)B * CAP * sizeof(uint64_t);
  float*    scores = (float*)p;     p += (size_t)N * sizeof(float);
  uint32_t* hist   = (uint32_t*)p;  p += (size_t)B * BINS * sizeof(uint32_t);
  uint32_t* cnt    = (uint32_t*)p;  p += (size_t)B * sizeof(uint32_t);   // adjacent to hist
  uint32_t* prank  = (uint32_t*)p;  p += (size_t)B * JSPLIT * CAP * sizeof(uint32_t);
  int*      top_n    = (int*)p;     p += (size_t)B * PRE_K * sizeof(int);
  int*      Cnum     = (int*)p;      p += (size_t)B * sizeof(int);
  p = (p + 255) & ~(uintptr_t)255;
  uint32_t* maskT    = (uint32_t*)p; p += (size_t)B * CH * ROWS * 2 * sizeof(uint32_t);
  // f32 box mirror overlays `scores` (dead after k_compact)
  float4*   tboxf  = (float4*)scores;
  float*    tareaf = (float*)(scores + (size_t)B * ROWS * 4);
  (void)ws_size; (void)n_in; (void)out_size;

  hipMemsetAsync(hist, 0, (size_t)(B * BINS + B) * sizeof(uint32_t), stream);
  k_score<<<(N + 4095) / 4096, 256, 0, stream>>>(anchors, bix, isz, logits, deltas,
                                                 scores, hist, N);
  k_compact<<<(N + 8191) / 8192, 1024, 0, stream>>>(scores, bix, hist, cnt, cand, N);
  k_rank<<<B * 32 * JSPLIT, 256, 0, stream>>>(cand, cnt, prank);
  k_place_gather<<<(B * CAP + 255) / 256, 256, 0, stream>>>(cand, cnt, prank,
                                                            anchors, deltas, isz,
                                                            tbox, tarea, tboxf,
                                                            tareaf, top_n, Cnum, B);
  dim3 iou_grid(CH, CH, B);
  k_iou_mat<<<iou_grid, 64, 0, stream>>>(tboxf, tareaf, tbox, tarea, Cnum, maskT);
  k_nms_reduce<<<B, 256, 0, stream>>>(maskT, tbox, Cnum, top_n, logits, deltas,
                                      out, B);
}

// Round 10
// 362.887 us; speedup vs baseline: 1.4794x; 1.4794x over previous
//
#include <hip/hip_runtime.h>
#include <stdint.h>

#define PRE_K   6000
#define POST_K  1000
#define CAP     8192      // candidate buffer per batch
#define BINS    1024
#define ROWS    6016      // 94*64, padded row count for NMS
#define CH      94        // ROWS/64 chunks
#define RC_CH   32        // off-diag mask tiles computed only for rc < RC_CH
#define JSPLIT  8         // k_rank comparison-range split
#define NEGF    -1000000000.0f
#define IOU_EPS 16.0f     // f32 decision margin; f32 abs error bound ~2

// ---- helpers ----------------------------------------------------------------

__device__ __forceinline__ uint32_t orderf(float f) {
  uint32_t u = __float_as_uint(f);
  return (u & 0x80000000u) ? ~u : (u | 0x80000000u);
}

__device__ __forceinline__ int score_bin(float sc) {
  int bin = (int)floorf((sc + 12.0f) * ((float)BINS / 24.0f));
  return bin < 0 ? 0 : (bin > BINS - 1 ? BINS - 1 : bin);
}

__device__ __forceinline__ int bin_slot(int bin) {
  return ((bin & 15) << 6) | (bin >> 4);
}

// full double-precision decode, matching the float64 numpy reference
__device__ __forceinline__ void decode_box(
    const float* __restrict__ anchors, const float* __restrict__ deltas,
    const int* __restrict__ isz, int n, int b,
    double& x1, double& y1, double& x2, double& y2, bool& valid) {
  double ax1 = (double)anchors[4 * n + 0], ay1 = (double)anchors[4 * n + 1];
  double ax2 = (double)anchors[4 * n + 2], ay2 = (double)anchors[4 * n + 3];
  double aw = ax2 - ax1, ah = ay2 - ay1;
  double acx = ax1 + 0.5 * aw, acy = ay1 + 0.5 * ah;
  double tx = (double)deltas[4 * n + 0], ty = (double)deltas[4 * n + 1];
  double tw = (double)deltas[4 * n + 2], th = (double)deltas[4 * n + 3];
  tw = tw < -10.0 ? -10.0 : (tw > 10.0 ? 10.0 : tw);
  th = th < -10.0 ? -10.0 : (th > 10.0 ? 10.0 : th);
  double px = acx + tx * aw, py = acy + ty * ah;
  double pw = aw * exp(tw), ph = ah * exp(th);
  double H = (double)isz[2 * b + 0], W = (double)isz[2 * b + 1];
  double wm = W - 1.0, hm = H - 1.0;
  x1 = px - 0.5 * pw; y1 = py - 0.5 * ph;
  x2 = px + 0.5 * pw; y2 = py + 0.5 * ph;
  x1 = fmin(fmax(x1, 0.0), wm); x2 = fmin(fmax(x2, 0.0), wm);
  y1 = fmin(fmax(y1, 0.0), hm); y2 = fmin(fmax(y2, 0.0), hm);
  valid = (x2 - x1 >= 16.0) && (y2 - y1 >= 16.0);
}

// exact f64 suppression test (bit-identical to the verified R2 path)
__device__ __forceinline__ bool iou_exact(const double* __restrict__ tbox,
                                          const double* __restrict__ tarea,
                                          size_t ri, size_t ci) {
  const double* pr = &tbox[ri * 4];
  const double* pc = &tbox[ci * 4];
  double w = fmin(pr[2], pc[2]) - fmax(pr[0], pc[0]); w = w > 0.0 ? w : 0.0;
  double h = fmin(pr[3], pc[3]) - fmax(pr[1], pc[1]); h = h > 0.0 ? h : 0.0;
  double it = w * h;
  return it > 0.7 * (tarea[ri] + tarea[ci] - it + 1e-9);
}

// ---- kernels ----------------------------------------------------------------

// Decode + validity + LDS-privatized histogram.
__global__ void __launch_bounds__(256) k_score(const float* __restrict__ anchors,
                                               const int* __restrict__ bix,
                                               const int* __restrict__ isz,
                                               const float* __restrict__ logits,
                                               const float* __restrict__ deltas,
                                               float* __restrict__ scores,
                                               uint32_t* __restrict__ hist, int N) {
  const int SPAN = 4096;
  int start = blockIdx.x * SPAN;
  int end = start + SPAN < N ? start + SPAN : N;
  __shared__ uint32_t lh[2][BINS];
  for (int i = threadIdx.x; i < 2 * BINS; i += 256) ((uint32_t*)lh)[i] = 0u;
  __shared__ int s_b0, s_b1;
  if (threadIdx.x == 0) { s_b0 = bix[start]; s_b1 = bix[end - 1]; }
  __syncthreads();
  int b0 = s_b0, b1 = s_b1;

  for (int n = start + (int)threadIdx.x; n < end; n += 256) {
    int b = bix[n];
    double x1, y1, x2, y2; bool valid;
    decode_box(anchors, deltas, isz, n, b, x1, y1, x2, y2, valid);
    float sc = valid ? logits[n] : NEGF;
    scores[n] = sc;
    if (valid) {
      int bin = score_bin(sc);
      if (b == b0)      atomicAdd(&lh[0][bin], 1u);
      else if (b == b1) atomicAdd(&lh[1][bin], 1u);
      else              atomicAdd(&hist[b * BINS + bin_slot(bin)], 1u);
    }
  }
  __syncthreads();
  for (int bin = threadIdx.x; bin < BINS; bin += 256) {
    uint32_t c0 = lh[0][bin];
    if (c0) atomicAdd(&hist[b0 * BINS + bin_slot(bin)], c0);
    if (b1 != b0) {
      uint32_t c1 = lh[1][bin];
      if (c1) atomicAdd(&hist[b1 * BINS + bin_slot(bin)], c1);
    }
  }
}

// Block-aggregated compaction with fused threshold scan.
__global__ void __launch_bounds__(1024) k_compact(const float* __restrict__ scores,
                                                  const int* __restrict__ bix,
                                                  const uint32_t* __restrict__ hist,
                                                  uint32_t* __restrict__ cnt,
                                                  uint64_t* __restrict__ cand, int N) {
  const int SPAN = 8192;
  int start = blockIdx.x * SPAN;
  int end = start + SPAN < N ? start + SPAN : N;
  int t = threadIdx.x;
  __shared__ int s_b0, s_b1;
  __shared__ uint32_t sh[BINS];
  __shared__ int s_bs;
  __shared__ uint32_t lcnt[8], lbase[8];
  if (t == 0) { s_b0 = bix[start]; s_b1 = bix[end - 1]; }
  if (t < 8) lcnt[t] = 0u;
  __syncthreads();
  int b0 = s_b0, b1 = s_b1;

  uint32_t bs0 = 0, bs1 = 0;
  for (int pass = 0; pass < 2; pass++) {
    int b = pass == 0 ? b0 : b1;
    if (pass == 1 && b1 == b0) { bs1 = bs0; break; }
    if (t < BINS) sh[t] = hist[b * BINS + bin_slot(t)];
    if (t == 0) s_bs = 0;
    __syncthreads();
    for (int off = 1; off < BINS; off <<= 1) {
      uint32_t v = (t < BINS && t + off < BINS) ? sh[t + off] : 0u;
      __syncthreads();
      if (t < BINS) sh[t] += v;
      __syncthreads();
    }
    if (t < BINS && sh[t] >= PRE_K) atomicMax(&s_bs, t);
    __syncthreads();
    if (pass == 0) bs0 = (uint32_t)s_bs; else bs1 = (uint32_t)s_bs;
    __syncthreads();
  }

  bool     predv[8];
  uint64_t keyv[8];
  uint32_t lposv[8];
  int      bv[8];
  int nt = 0;
  for (int base = start; base < end; base += 1024, nt++) {
    int n = base + t;
    bool pred = false; int b = 0; uint64_t key = 0ull; uint32_t lp = 0u;
    if (n < end) {
      float sc = scores[n];
      if (sc > 0.5f * NEGF) {
        b = bix[n];
        uint32_t bs = (b == b0) ? bs0 : bs1;
        if ((uint32_t)score_bin(sc) >= bs) {
          pred = true;
          key = ((uint64_t)orderf(sc) << 32) | (uint64_t)(uint32_t)(~(uint32_t)n);
          lp = atomicAdd(&lcnt[b], 1u);
        }
      }
    }
    predv[nt] = pred; keyv[nt] = key; lposv[nt] = lp; bv[nt] = b;
  }
  __syncthreads();
  if (t < 8) {
    uint32_t c = lcnt[t];
    lbase[t] = c ? atomicAdd(&cnt[t], c) : 0u;
  }
  __syncthreads();
  for (int k = 0; k < nt; k++) {
    if (predv[k]) {
      uint32_t pos = lbase[bv[k]] + lposv[k];
      if (pos < CAP) cand[(size_t)bv[k] * CAP + pos] = keyv[k];
    }
  }
}

// Partial rank-by-count; each (b,ic,js) block writes its partial rank slice
// unconditionally (no zero-init needed). grid = B*32*JSPLIT x 256.
__global__ void __launch_bounds__(256) k_rank(const uint64_t* __restrict__ cand,
                                              const uint32_t* __restrict__ cnt,
                                              uint32_t* __restrict__ prank) {
  int blk = blockIdx.x;
  int js = blk % JSPLIT;
  int ic = (blk / JSPLIT) % 32;
  int b  = blk / (JSPLIT * 32);
  int t = threadIdx.x;
  int C = (int)min(cnt[b], (uint32_t)CAP);
  if (ic * 256 >= C) return;
  const uint64_t* g = cand + (size_t)b * CAP;
  int i = ic * 256 + t;
  uint64_t ki = (i < C) ? g[i] : 0ull;

  int q = (C + JSPLIT - 1) / JSPLIT;
  int j0 = js * q;
  int j1 = j0 + q < C ? j0 + q : C;

  __shared__ uint64_t tile[1024];
  int rank = 0;
  for (int base = j0; base < j1; base += 1024) {
#pragma unroll
    for (int u = 0; u < 4; u++) {
      int j = base + u * 256 + t;
      tile[u * 256 + t] = (j < j1) ? g[j] : 0ull;
    }
    __syncthreads();
    int lim = j1 - base < 1024 ? j1 - base : 1024;
    const ulonglong2* t2 = (const ulonglong2*)tile;
    int pairs = lim >> 1;
    int jj = 0;
    for (; jj + 4 <= pairs; jj += 4) {
      ulonglong2 v0 = t2[jj + 0], v1 = t2[jj + 1];
      ulonglong2 v2 = t2[jj + 2], v3 = t2[jj + 3];
      rank += (v0.x > ki) ? 1 : 0; rank += (v0.y > ki) ? 1 : 0;
      rank += (v1.x > ki) ? 1 : 0; rank += (v1.y > ki) ? 1 : 0;
      rank += (v2.x > ki) ? 1 : 0; rank += (v2.y > ki) ? 1 : 0;
      rank += (v3.x > ki) ? 1 : 0; rank += (v3.y > ki) ? 1 : 0;
    }
    for (; jj < pairs; jj++) {
      ulonglong2 v = t2[jj];
      rank += (v.x > ki) ? 1 : 0; rank += (v.y > ki) ? 1 : 0;
    }
    if (lim & 1) rank += (tile[lim - 1] > ki) ? 1 : 0;
    __syncthreads();
  }
  if (i < C) prank[((size_t)b * JSPLIT + js) * CAP + i] = (uint32_t)rank;
}

// Fused place + gather: sums the JSPLIT partial ranks, then decodes the box
// directly into row=rank (f64 + f32 mirrors).
__global__ void __launch_bounds__(256) k_place_gather(
    const uint64_t* __restrict__ cand, const uint32_t* __restrict__ cnt,
    const uint32_t* __restrict__ prank,
    const float* __restrict__ anchors, const float* __restrict__ deltas,
    const int* __restrict__ isz,
    double* __restrict__ tbox, double* __restrict__ tarea,
    float4* __restrict__ tboxf, float* __restrict__ tareaf,
    int* __restrict__ top_n, int* __restrict__ Cnum, int B) {
  int idx = blockIdx.x * blockDim.x + threadIdx.x;
  if (idx >= B * CAP) return;
  int b = idx / CAP, i = idx % CAP;
  int C = (int)min(cnt[b], (uint32_t)CAP);
  if (i == 0) Cnum[b] = C < PRE_K ? C : PRE_K;
  if (i >= C) return;
  uint32_t rank = 0;
#pragma unroll
  for (int js = 0; js < JSPLIT; js++)
    rank += prank[((size_t)b * JSPLIT + js) * CAP + i];
  if (rank >= PRE_K) return;
  int n = (int)(~(uint32_t)(cand[idx] & 0xFFFFFFFFull));
  double x1, y1, x2, y2; bool valid;
  decode_box(anchors, deltas, isz, n, b, x1, y1, x2, y2, valid);
  size_t row = (size_t)b * ROWS + rank;
  tbox[row * 4 + 0] = x1;
  tbox[row * 4 + 1] = y1;
  tbox[row * 4 + 2] = x2;
  tbox[row * 4 + 3] = y2;
  double ar = (x2 - x1) * (y2 - y1);
  tarea[row] = ar;
  tboxf[row] = make_float4((float)x1, (float)y1, (float)x2, (float)y2);
  tareaf[row] = (float)ar;
  top_n[b * PRE_K + rank] = n;
}

// Suppression bit tiles, capped: all diagonals + off-diag rc < RC_CH.
// Chunk-major transposed layout: maskT[((b*CH + cc)*ROWS + row)*2 + w].
// Diag tiles ALSO emit the transposed diag (lane j's word = rows killing
// column j) into diagT — consumed by the shuffle-free greedy in k_nms_reduce.
__global__ void __launch_bounds__(64) k_iou_mat(const float4* __restrict__ tboxf,
                                                const float* __restrict__ tareaf,
                                                const double* __restrict__ tbox,
                                                const double* __restrict__ tarea,
                                                const int* __restrict__ Cnum,
                                                uint32_t* __restrict__ maskT,
                                                uint32_t* __restrict__ diagT) {
  int blk = blockIdx.x;
  int k  = blk % (RC_CH + 1);
  int cc = (blk / (RC_CH + 1)) % CH;
  int b  = blk / ((RC_CH + 1) * CH);
  int rc = (k == RC_CH) ? cc : k;
  if (k < RC_CH && cc <= rc) return;
  int C = Cnum[b];
  if (rc * 64 >= C || cc * 64 >= C) return;
  int lane = threadIdx.x;
  size_t bb = (size_t)b * ROWS;

  float4 cb4 = tboxf[bb + (size_t)cc * 64 + lane];
  float  sca = 0.7f * tareaf[bb + (size_t)cc * 64 + lane];
  __shared__ float4 rbx[64];
  __shared__ float  rsa[64];
  rbx[lane] = tboxf[bb + (size_t)rc * 64 + lane];
  rsa[lane] = 0.7f * tareaf[bb + (size_t)rc * 64 + lane];
  __syncthreads();

  bool isdiag = (rc == cc);
  uint32_t res0 = 0u, res1 = 0u;
  uint32_t t0 = 0u, t1 = 0u;   // transposed diag accumulation (column words)

  for (int i = 0; i < 64; i++) {
    float4 r4 = rbx[i];
    float sra = rsa[i];
    float iw = fminf(r4.z, cb4.z) - fmaxf(r4.x, cb4.x);
    float ih = fminf(r4.w, cb4.w) - fmaxf(r4.y, cb4.y);
    iw = fmaxf(iw, 0.0f); ih = fmaxf(ih, 0.0f);
    float inter = iw * ih;
    float diff = fmaf(1.7f, inter, -(sra + sca));
    bool gt = isdiag ? (lane > i) : true;
    unsigned long long sup   = __ballot(gt && (diff >  IOU_EPS));
    unsigned long long loose = __ballot(gt && (diff > -IOU_EPS));
    unsigned long long border = loose & ~sup;
    if (border) {
      bool mine = (border >> lane) & 1ull;
      bool ex = false;
      if (mine)
        ex = iou_exact(tbox, tarea, bb + (size_t)rc * 64 + i,
                       bb + (size_t)cc * 64 + lane);
      sup |= __ballot(ex);
    }
    if (isdiag && ((sup >> lane) & 1ull)) {
      if (i < 32) t0 |= 1u << i; else t1 |= 1u << (i - 32);
    }
    if (lane == i) { res0 = (uint32_t)sup; res1 = (uint32_t)(sup >> 32); }
  }
  uint2* seg = (uint2*)(maskT + (((size_t)b * CH + cc) * ROWS + (size_t)rc * 64) * 2);
  seg[lane] = make_uint2(res0, res1);
  if (isdiag) {
    ((uint2*)diagT)[((size_t)b * CH + rc) * 64 + lane] = make_uint2(t0, t1);
  }
}

// R12's known-best greedy resolve (94 chunks) + fused output tail, with a
// SHUFFLE-FREE greedy: lane j holds the transposed diag word T_j (rows that
// kill column j), so each step is ballot -> ctz -> per-lane bit test —
// no dependent ds_bpermute on the serial chain. Kept order is identical.
__global__ void __launch_bounds__(256) k_nms_reduce(const uint32_t* __restrict__ maskT,
                                                    const uint32_t* __restrict__ diagT,
                                                    const float4* __restrict__ tboxf,
                                                    const float* __restrict__ tareaf,
                                                    const double* __restrict__ tbox,
                                                    const double* __restrict__ tarea,
                                                    const int* __restrict__ Cnum,
                                                    const int* __restrict__ top_n,
                                                    const float* __restrict__ logits,
                                                    const float* __restrict__ deltas,
                                                    float* __restrict__ out, int B) {
  int b = blockIdx.x, t = threadIdx.x;
  int wave = t >> 6, lane = t & 63;
  int C = Cnum[b];
  const uint32_t* M = maskT + (size_t)b * CH * ROWS * 2;
  const uint2* DT = (const uint2*)diagT + (size_t)b * CH * 64;
  size_t bb = (size_t)b * ROWS;

  __shared__ uint32_t s_f[2][2];
  __shared__ uint32_t kept_lo[POST_K];
  __shared__ uint32_t kept_hi[POST_K];
  __shared__ uint64_t s_kept;
  if (t < 4) ((uint32_t*)s_f)[t] = 0u;

  uint32_t d0 = 0u, d1 = 0u;   // transposed diag words for the current chunk
  if (wave == 0) {
    uint2 td = DT[lane];
    d0 = td.x; d1 = td.y;
  }
  __syncthreads();

  int nkept = 0, nlo = 0, nhi = 0;
  for (int c = 0; c < CH; c++) {
    int base = c * 64;
    if (base >= C) break;
    int cbuf = c & 1;
    if (t == 0) { s_f[cbuf ^ 1][0] = 0u; s_f[cbuf ^ 1][1] = 0u; }

    // phase A: precomputed mask rows (kept_lo)
    uint32_t f0 = 0u, f1 = 0u;
    for (int k2 = t; k2 < nlo; k2 += 256) {
      const uint32_t* rp = M + ((size_t)c * ROWS + kept_lo[k2]) * 2;
      f0 |= rp[0]; f1 |= rp[1];
    }
    // phase B: on-the-fly (kept_hi), split across 4 waves
    if (nhi > 0) {
      float4 cb4 = tboxf[bb + base + lane];
      float  sca = 0.7f * tareaf[bb + base + lane];
      for (int k2 = wave; k2 < nhi; k2 += 4) {
        int r = (int)kept_hi[k2];
        float4 r4 = tboxf[bb + r];
        float sra = 0.7f * tareaf[bb + r];
        float iw = fminf(r4.z, cb4.z) - fmaxf(r4.x, cb4.x);
        float ih = fminf(r4.w, cb4.w) - fmaxf(r4.y, cb4.y);
        iw = fmaxf(iw, 0.0f); ih = fmaxf(ih, 0.0f);
        float inter = iw * ih;
        float diff = fmaf(1.7f, inter, -(sra + sca));
        unsigned long long sup   = __ballot(diff >  IOU_EPS);
        unsigned long long loose = __ballot(diff > -IOU_EPS);
        unsigned long long border = loose & ~sup;
        if (border) {
          bool mine = (border >> lane) & 1ull;
          bool ex = false;
          if (mine) ex = iou_exact(tbox, tarea, bb + r, bb + base + lane);
          sup |= __ballot(ex);
        }
        f0 |= (uint32_t)sup; f1 |= (uint32_t)(sup >> 32);
      }
    }
#pragma unroll
    for (int off = 32; off > 0; off >>= 1) {
      f0 |= (uint32_t)__shfl_xor((int)f0, off, 64);
      f1 |= (uint32_t)__shfl_xor((int)f1, off, 64);
    }
    if (lane == 0 && (f0 | f1)) {
      atomicOr(&s_f[cbuf][0], f0);
      atomicOr(&s_f[cbuf][1], f1);
    }
    __syncthreads();

    if (wave == 0) {
      uint64_t sup = (uint64_t)s_f[cbuf][0] | ((uint64_t)s_f[cbuf][1] << 32);
      int rem = C - base;
      if (rem < 64) sup |= ~((1ull << rem) - 1ull);
      uint64_t Tj = (uint64_t)d0 | ((uint64_t)d1 << 32);
      int cn = (c + 1 < CH) ? c + 1 : c;
      uint2 tdn = DT[(size_t)cn * 64 + lane];   // prefetch next chunk's T

      // shuffle-free greedy: ballot -> ctz -> per-lane T bit test
      bool aliveMine = !((sup >> lane) & 1ull);
      uint64_t keptMask = 0ull;
      for (;;) {
        unsigned long long bal = __ballot(aliveMine);
        if (!bal) break;
        int i = __builtin_ctzll(bal);
        keptMask |= 1ull << i;
        aliveMine = aliveMine && (lane != i) && !((Tj >> i) & 1ull);
      }
      int allowed = POST_K - nkept;
      int pc = __popcll(keptMask);
      while (pc > allowed) {
        keptMask &= ~(1ull << (63 - __builtin_clzll(keptMask)));
        pc--;
      }
      if (lane == 0) s_kept = keptMask;
      if ((keptMask >> lane) & 1ull) {
        int pfx = __popcll(keptMask & ((1ull << lane) - 1ull));
        int row = base + lane;
        if (c < RC_CH) kept_lo[nlo + pfx] = (uint32_t)row;
        else           kept_hi[nhi + pfx] = (uint32_t)row;
      }
      d0 = tdn.x; d1 = tdn.y;
    }
    __syncthreads();

    int pc = __popcll(s_kept);
    nkept += pc;
    if (c < RC_CH) nlo += pc; else nhi += pc;
    if (nkept >= POST_K) break;
  }

  // ---- fused output: block writes its batch's POST_K rows ----
  __syncthreads();
  int M_out = B * POST_K;
  for (int s2 = t; s2 < POST_K; s2 += 256) {
    float p0 = 0.f, p1 = 0.f, p2 = 0.f, p3 = 0.f;
    float ob = 0.f, d0f = 0.f, d1f = 0.f, d2f = 0.f, d3f = 0.f;
    float bi = -1.0f, okv = 0.0f;
    if (s2 < nkept) {
      int j = (s2 < nlo) ? (int)kept_lo[s2] : (int)kept_hi[s2 - nlo];
      int n = top_n[b * PRE_K + j];
      const double* p = &tbox[(bb + j) * 4];
      p0 = (float)p[0]; p1 = (float)p[1]; p2 = (float)p[2]; p3 = (float)p[3];
      ob = logits[n];
      d0f = deltas[4 * n + 0]; d1f = deltas[4 * n + 1];
      d2f = deltas[4 * n + 2]; d3f = deltas[4 * n + 3];
      bi = (float)b; okv = 1.0f;
    }
    int idx = b * POST_K + s2;
    out[idx * 4 + 0] = p0;
    out[idx * 4 + 1] = p1;
    out[idx * 4 + 2] = p2;
    out[idx * 4 + 3] = p3;
    out[4 * M_out + idx] = bi;
    out[5 * M_out + idx] = ob;
    out[6 * M_out + idx * 4 + 0] = d0f;
    out[6 * M_out + idx * 4 + 1] = d1f;
    out[6 * M_out + idx * 4 + 2] = d2f;
    out[6 * M_out + idx * 4 + 3] = d3f;
    out[10 * M_out + idx] = okv;
  }
}

// ---- launch -----------------------------------------------------------------

extern "C" void kernel_launch(void* const* d_in, const int* in_sizes, int n_in,
                              void* d_out, int out_size, void* d_ws, size_t ws_size,
                              hipStream_t stream) {
  const float* anchors = (const float*)d_in[0];
  const int*   bix     = (const int*)d_in[1];
  const int*   isz     = (const int*)d_in[2];
  const float* logits  = (const float*)d_in[3];
  const float* deltas  = (const float*)d_in[4];
  float* out = (float*)d_out;

  int N = in_sizes[1];
  int B = in_sizes[2] / 2;

  uintptr_t p = (uintptr_t)d_ws;
  double*   tbox   = (double*)p;    p += (size_t)B * ROWS * 4 * sizeof(double);
  double*   tarea  = (double*)p;    p += (size_t)B * ROWS * sizeof(double);
  uint64_t* cand   = (uint64_t*)p;  p += (size_t)B * CAP * sizeof(uint64_t);
  float*    scores = (float*)p;     p += (size_t)N * sizeof(float);
  uint32_t* hist   = (uint32_t*)p;  p += (size_t)B * BINS * sizeof(uint32_t);
  uint32_t* cnt    = (uint32_t*)p;  p += (size_t)B * sizeof(uint32_t);   // adjacent to hist
  uint32_t* prank  = (uint32_t*)p;  p += (size_t)B * JSPLIT * CAP * sizeof(uint32_t);
  int*      top_n    = (int*)p;     p += (size_t)B * PRE_K * sizeof(int);
  int*      Cnum     = (int*)p;      p += (size_t)B * sizeof(int);
  p = (p + 255) & ~(uintptr_t)255;
  uint32_t* maskT    = (uint32_t*)p; p += (size_t)B * CH * ROWS * 2 * sizeof(uint32_t);
  p = (p + 255) & ~(uintptr_t)255;
  uint32_t* diagT    = (uint32_t*)p; p += (size_t)B * CH * 64 * 2 * sizeof(uint32_t);
  // f32 box mirror overlays `scores` (dead after k_compact)
  float4*   tboxf  = (float4*)scores;
  float*    tareaf = (float*)(scores + (size_t)B * ROWS * 4);
  (void)ws_size; (void)n_in; (void)out_size;

  hipMemsetAsync(hist, 0, (size_t)(B * BINS + B) * sizeof(uint32_t), stream);
  k_score<<<(N + 4095) / 4096, 256, 0, stream>>>(anchors, bix, isz, logits, deltas,
                                                 scores, hist, N);
  k_compact<<<(N + 8191) / 8192, 1024, 0, stream>>>(scores, bix, hist, cnt, cand, N);
  k_rank<<<B * 32 * JSPLIT, 256, 0, stream>>>(cand, cnt, prank);
  k_place_gather<<<(B * CAP + 255) / 256, 256, 0, stream>>>(cand, cnt, prank,
                                                            anchors, deltas, isz,
                                                            tbox, tarea, tboxf,
                                                            tareaf, top_n, Cnum, B);
  k_iou_mat<<<B * CH * (RC_CH + 1), 64, 0, stream>>>(tboxf, tareaf, tbox, tarea,
                                                     Cnum, maskT, diagT);
  k_nms_reduce<<<B, 256, 0, stream>>>(maskT, diagT, tboxf, tareaf, tbox, tarea,
                                      Cnum, top_n, logits, deltas, out, B);
}

// Round 11
// 362.066 us; speedup vs baseline: 1.4828x; 1.0023x over previous
//
#include <hip/hip_runtime.h>
#include <stdint.h>

#define PRE_K   6000
#define POST_K  1000
#define CAP     8192      // candidate buffer per batch
#define BINS    1024
#define ROWS    6016      // 94*64, padded row count for NMS
#define CH      94        // ROWS/64 chunks
#define RC_CH   32        // off-diag mask tiles computed only for rc < RC_CH
#define JSPLIT  8         // k_rank comparison-range split
#define NEGF    -1000000000.0f
#define IOU_EPS 16.0f     // f32 decision margin; f32 abs error bound ~2

// ---- helpers ----------------------------------------------------------------

__device__ __forceinline__ uint32_t orderf(float f) {
  uint32_t u = __float_as_uint(f);
  return (u & 0x80000000u) ? ~u : (u | 0x80000000u);
}

__device__ __forceinline__ int score_bin(float sc) {
  int bin = (int)floorf((sc + 12.0f) * ((float)BINS / 24.0f));
  return bin < 0 ? 0 : (bin > BINS - 1 ? BINS - 1 : bin);
}

__device__ __forceinline__ int bin_slot(int bin) {
  return ((bin & 15) << 6) | (bin >> 4);
}

// full double-precision decode, matching the float64 numpy reference
__device__ __forceinline__ void decode_box(
    const float* __restrict__ anchors, const float* __restrict__ deltas,
    const int* __restrict__ isz, int n, int b,
    double& x1, double& y1, double& x2, double& y2, bool& valid) {
  double ax1 = (double)anchors[4 * n + 0], ay1 = (double)anchors[4 * n + 1];
  double ax2 = (double)anchors[4 * n + 2], ay2 = (double)anchors[4 * n + 3];
  double aw = ax2 - ax1, ah = ay2 - ay1;
  double acx = ax1 + 0.5 * aw, acy = ay1 + 0.5 * ah;
  double tx = (double)deltas[4 * n + 0], ty = (double)deltas[4 * n + 1];
  double tw = (double)deltas[4 * n + 2], th = (double)deltas[4 * n + 3];
  tw = tw < -10.0 ? -10.0 : (tw > 10.0 ? 10.0 : tw);
  th = th < -10.0 ? -10.0 : (th > 10.0 ? 10.0 : th);
  double px = acx + tx * aw, py = acy + ty * ah;
  double pw = aw * exp(tw), ph = ah * exp(th);
  double H = (double)isz[2 * b + 0], W = (double)isz[2 * b + 1];
  double wm = W - 1.0, hm = H - 1.0;
  x1 = px - 0.5 * pw; y1 = py - 0.5 * ph;
  x2 = px + 0.5 * pw; y2 = py + 0.5 * ph;
  x1 = fmin(fmax(x1, 0.0), wm); x2 = fmin(fmax(x2, 0.0), wm);
  y1 = fmin(fmax(y1, 0.0), hm); y2 = fmin(fmax(y2, 0.0), hm);
  valid = (x2 - x1 >= 16.0) && (y2 - y1 >= 16.0);
}

// exact f64 suppression test (bit-identical to the verified R2 path)
__device__ __forceinline__ bool iou_exact(const double* __restrict__ tbox,
                                          const double* __restrict__ tarea,
                                          size_t ri, size_t ci) {
  const double* pr = &tbox[ri * 4];
  const double* pc = &tbox[ci * 4];
  double w = fmin(pr[2], pc[2]) - fmax(pr[0], pc[0]); w = w > 0.0 ? w : 0.0;
  double h = fmin(pr[3], pc[3]) - fmax(pr[1], pc[1]); h = h > 0.0 ? h : 0.0;
  double it = w * h;
  return it > 0.7 * (tarea[ri] + tarea[ci] - it + 1e-9);
}

// ---- kernels ----------------------------------------------------------------

// Decode + validity + LDS-privatized histogram.
__global__ void __launch_bounds__(256) k_score(const float* __restrict__ anchors,
                                               const int* __restrict__ bix,
                                               const int* __restrict__ isz,
                                               const float* __restrict__ logits,
                                               const float* __restrict__ deltas,
                                               float* __restrict__ scores,
                                               uint32_t* __restrict__ hist, int N) {
  const int SPAN = 4096;
  int start = blockIdx.x * SPAN;
  int end = start + SPAN < N ? start + SPAN : N;
  __shared__ uint32_t lh[2][BINS];
  for (int i = threadIdx.x; i < 2 * BINS; i += 256) ((uint32_t*)lh)[i] = 0u;
  __shared__ int s_b0, s_b1;
  if (threadIdx.x == 0) { s_b0 = bix[start]; s_b1 = bix[end - 1]; }
  __syncthreads();
  int b0 = s_b0, b1 = s_b1;

  for (int n = start + (int)threadIdx.x; n < end; n += 256) {
    int b = bix[n];
    double x1, y1, x2, y2; bool valid;
    decode_box(anchors, deltas, isz, n, b, x1, y1, x2, y2, valid);
    float sc = valid ? logits[n] : NEGF;
    scores[n] = sc;
    if (valid) {
      int bin = score_bin(sc);
      if (b == b0)      atomicAdd(&lh[0][bin], 1u);
      else if (b == b1) atomicAdd(&lh[1][bin], 1u);
      else              atomicAdd(&hist[b * BINS + bin_slot(bin)], 1u);
    }
  }
  __syncthreads();
  for (int bin = threadIdx.x; bin < BINS; bin += 256) {
    uint32_t c0 = lh[0][bin];
    if (c0) atomicAdd(&hist[b0 * BINS + bin_slot(bin)], c0);
    if (b1 != b0) {
      uint32_t c1 = lh[1][bin];
      if (c1) atomicAdd(&hist[b1 * BINS + bin_slot(bin)], c1);
    }
  }
}

// Block-aggregated compaction with fused threshold scan.
__global__ void __launch_bounds__(1024) k_compact(const float* __restrict__ scores,
                                                  const int* __restrict__ bix,
                                                  const uint32_t* __restrict__ hist,
                                                  uint32_t* __restrict__ cnt,
                                                  uint64_t* __restrict__ cand, int N) {
  const int SPAN = 8192;
  int start = blockIdx.x * SPAN;
  int end = start + SPAN < N ? start + SPAN : N;
  int t = threadIdx.x;
  __shared__ int s_b0, s_b1;
  __shared__ uint32_t sh[BINS];
  __shared__ int s_bs;
  __shared__ uint32_t lcnt[8], lbase[8];
  if (t == 0) { s_b0 = bix[start]; s_b1 = bix[end - 1]; }
  if (t < 8) lcnt[t] = 0u;
  __syncthreads();
  int b0 = s_b0, b1 = s_b1;

  uint32_t bs0 = 0, bs1 = 0;
  for (int pass = 0; pass < 2; pass++) {
    int b = pass == 0 ? b0 : b1;
    if (pass == 1 && b1 == b0) { bs1 = bs0; break; }
    if (t < BINS) sh[t] = hist[b * BINS + bin_slot(t)];
    if (t == 0) s_bs = 0;
    __syncthreads();
    for (int off = 1; off < BINS; off <<= 1) {
      uint32_t v = (t < BINS && t + off < BINS) ? sh[t + off] : 0u;
      __syncthreads();
      if (t < BINS) sh[t] += v;
      __syncthreads();
    }
    if (t < BINS && sh[t] >= PRE_K) atomicMax(&s_bs, t);
    __syncthreads();
    if (pass == 0) bs0 = (uint32_t)s_bs; else bs1 = (uint32_t)s_bs;
    __syncthreads();
  }

  bool     predv[8];
  uint64_t keyv[8];
  uint32_t lposv[8];
  int      bv[8];
  int nt = 0;
  for (int base = start; base < end; base += 1024, nt++) {
    int n = base + t;
    bool pred = false; int b = 0; uint64_t key = 0ull; uint32_t lp = 0u;
    if (n < end) {
      float sc = scores[n];
      if (sc > 0.5f * NEGF) {
        b = bix[n];
        uint32_t bs = (b == b0) ? bs0 : bs1;
        if ((uint32_t)score_bin(sc) >= bs) {
          pred = true;
          key = ((uint64_t)orderf(sc) << 32) | (uint64_t)(uint32_t)(~(uint32_t)n);
          lp = atomicAdd(&lcnt[b], 1u);
        }
      }
    }
    predv[nt] = pred; keyv[nt] = key; lposv[nt] = lp; bv[nt] = b;
  }
  __syncthreads();
  if (t < 8) {
    uint32_t c = lcnt[t];
    lbase[t] = c ? atomicAdd(&cnt[t], c) : 0u;
  }
  __syncthreads();
  for (int k = 0; k < nt; k++) {
    if (predv[k]) {
      uint32_t pos = lbase[bv[k]] + lposv[k];
      if (pos < CAP) cand[(size_t)bv[k] * CAP + pos] = keyv[k];
    }
  }
}

// Partial rank-by-count; each (b,ic,js) block writes its partial rank slice
// unconditionally (no zero-init needed). grid = B*32*JSPLIT x 256.
__global__ void __launch_bounds__(256) k_rank(const uint64_t* __restrict__ cand,
                                              const uint32_t* __restrict__ cnt,
                                              uint32_t* __restrict__ prank) {
  int blk = blockIdx.x;
  int js = blk % JSPLIT;
  int ic = (blk / JSPLIT) % 32;
  int b  = blk / (JSPLIT * 32);
  int t = threadIdx.x;
  int C = (int)min(cnt[b], (uint32_t)CAP);
  if (ic * 256 >= C) return;
  const uint64_t* g = cand + (size_t)b * CAP;
  int i = ic * 256 + t;
  uint64_t ki = (i < C) ? g[i] : 0ull;

  int q = (C + JSPLIT - 1) / JSPLIT;
  int j0 = js * q;
  int j1 = j0 + q < C ? j0 + q : C;

  __shared__ uint64_t tile[1024];
  int rank = 0;
  for (int base = j0; base < j1; base += 1024) {
#pragma unroll
    for (int u = 0; u < 4; u++) {
      int j = base + u * 256 + t;
      tile[u * 256 + t] = (j < j1) ? g[j] : 0ull;
    }
    __syncthreads();
    int lim = j1 - base < 1024 ? j1 - base : 1024;
    const ulonglong2* t2 = (const ulonglong2*)tile;
    int pairs = lim >> 1;
    int jj = 0;
    for (; jj + 4 <= pairs; jj += 4) {
      ulonglong2 v0 = t2[jj + 0], v1 = t2[jj + 1];
      ulonglong2 v2 = t2[jj + 2], v3 = t2[jj + 3];
      rank += (v0.x > ki) ? 1 : 0; rank += (v0.y > ki) ? 1 : 0;
      rank += (v1.x > ki) ? 1 : 0; rank += (v1.y > ki) ? 1 : 0;
      rank += (v2.x > ki) ? 1 : 0; rank += (v2.y > ki) ? 1 : 0;
      rank += (v3.x > ki) ? 1 : 0; rank += (v3.y > ki) ? 1 : 0;
    }
    for (; jj < pairs; jj++) {
      ulonglong2 v = t2[jj];
      rank += (v.x > ki) ? 1 : 0; rank += (v.y > ki) ? 1 : 0;
    }
    if (lim & 1) rank += (tile[lim - 1] > ki) ? 1 : 0;
    __syncthreads();
  }
  if (i < C) prank[((size_t)b * JSPLIT + js) * CAP + i] = (uint32_t)rank;
}

// Fused place + gather: sums the JSPLIT partial ranks, then decodes the box
// directly into row=rank (f64 + f32 mirrors).
__global__ void __launch_bounds__(256) k_place_gather(
    const uint64_t* __restrict__ cand, const uint32_t* __restrict__ cnt,
    const uint32_t* __restrict__ prank,
    const float* __restrict__ anchors, const float* __restrict__ deltas,
    const int* __restrict__ isz,
    double* __restrict__ tbox, double* __restrict__ tarea,
    float4* __restrict__ tboxf, float* __restrict__ tareaf,
    int* __restrict__ top_n, int* __restrict__ Cnum, int B) {
  int idx = blockIdx.x * blockDim.x + threadIdx.x;
  if (idx >= B * CAP) return;
  int b = idx / CAP, i = idx % CAP;
  int C = (int)min(cnt[b], (uint32_t)CAP);
  if (i == 0) Cnum[b] = C < PRE_K ? C : PRE_K;
  if (i >= C) return;
  uint32_t rank = 0;
#pragma unroll
  for (int js = 0; js < JSPLIT; js++)
    rank += prank[((size_t)b * JSPLIT + js) * CAP + i];
  if (rank >= PRE_K) return;
  int n = (int)(~(uint32_t)(cand[idx] & 0xFFFFFFFFull));
  double x1, y1, x2, y2; bool valid;
  decode_box(anchors, deltas, isz, n, b, x1, y1, x2, y2, valid);
  size_t row = (size_t)b * ROWS + rank;
  tbox[row * 4 + 0] = x1;
  tbox[row * 4 + 1] = y1;
  tbox[row * 4 + 2] = x2;
  tbox[row * 4 + 3] = y2;
  double ar = (x2 - x1) * (y2 - y1);
  tarea[row] = ar;
  tboxf[row] = make_float4((float)x1, (float)y1, (float)x2, (float)y2);
  tareaf[row] = (float)ar;
  top_n[b * PRE_K + rank] = n;
}

// Suppression bit tiles, capped: all diagonals + off-diag rc < RC_CH.
// Chunk-major transposed layout: maskT[((b*CH + cc)*ROWS + row)*2 + w].
// Diag tiles ALSO emit the transposed diag (lane j's word = rows killing
// column j) into diagT — consumed by the shuffle-free greedy in k_nms_reduce.
__global__ void __launch_bounds__(64) k_iou_mat(const float4* __restrict__ tboxf,
                                                const float* __restrict__ tareaf,
                                                const double* __restrict__ tbox,
                                                const double* __restrict__ tarea,
                                                const int* __restrict__ Cnum,
                                                uint32_t* __restrict__ maskT,
                                                uint32_t* __restrict__ diagT) {
  int blk = blockIdx.x;
  int k  = blk % (RC_CH + 1);
  int cc = (blk / (RC_CH + 1)) % CH;
  int b  = blk / ((RC_CH + 1) * CH);
  int rc = (k == RC_CH) ? cc : k;
  if (k < RC_CH && cc <= rc) return;
  int C = Cnum[b];
  if (rc * 64 >= C || cc * 64 >= C) return;
  int lane = threadIdx.x;
  size_t bb = (size_t)b * ROWS;

  float4 cb4 = tboxf[bb + (size_t)cc * 64 + lane];
  float  sca = 0.7f * tareaf[bb + (size_t)cc * 64 + lane];
  __shared__ float4 rbx[64];
  __shared__ float  rsa[64];
  rbx[lane] = tboxf[bb + (size_t)rc * 64 + lane];
  rsa[lane] = 0.7f * tareaf[bb + (size_t)rc * 64 + lane];
  __syncthreads();

  bool isdiag = (rc == cc);
  uint32_t res0 = 0u, res1 = 0u;
  uint32_t t0 = 0u, t1 = 0u;   // transposed diag accumulation (column words)

  for (int i = 0; i < 64; i++) {
    float4 r4 = rbx[i];
    float sra = rsa[i];
    float iw = fminf(r4.z, cb4.z) - fmaxf(r4.x, cb4.x);
    float ih = fminf(r4.w, cb4.w) - fmaxf(r4.y, cb4.y);
    iw = fmaxf(iw, 0.0f); ih = fmaxf(ih, 0.0f);
    float inter = iw * ih;
    float diff = fmaf(1.7f, inter, -(sra + sca));
    bool gt = isdiag ? (lane > i) : true;
    unsigned long long sup   = __ballot(gt && (diff >  IOU_EPS));
    unsigned long long loose = __ballot(gt && (diff > -IOU_EPS));
    unsigned long long border = loose & ~sup;
    if (border) {
      bool mine = (border >> lane) & 1ull;
      bool ex = false;
      if (mine)
        ex = iou_exact(tbox, tarea, bb + (size_t)rc * 64 + i,
                       bb + (size_t)cc * 64 + lane);
      sup |= __ballot(ex);
    }
    if (isdiag && ((sup >> lane) & 1ull)) {
      if (i < 32) t0 |= 1u << i; else t1 |= 1u << (i - 32);
    }
    if (lane == i) { res0 = (uint32_t)sup; res1 = (uint32_t)(sup >> 32); }
  }
  uint2* seg = (uint2*)(maskT + (((size_t)b * CH + cc) * ROWS + (size_t)rc * 64) * 2);
  seg[lane] = make_uint2(res0, res1);
  if (isdiag) {
    ((uint2*)diagT)[((size_t)b * CH + rc) * 64 + lane] = make_uint2(t0, t1);
  }
}

// Greedy resolve + fused output tail. Phase B is BALLOT-FREE: lane j only
// accumulates its own column's suppression bit (bool supMine) — no per-row
// cross-lane ops; one ballot per wave per chunk converts to word form.
// Greedy uses the transposed diag (diagT): ballot -> ctz -> per-lane bit test.
__global__ void __launch_bounds__(256) k_nms_reduce(const uint32_t* __restrict__ maskT,
                                                    const uint32_t* __restrict__ diagT,
                                                    const float4* __restrict__ tboxf,
                                                    const float* __restrict__ tareaf,
                                                    const double* __restrict__ tbox,
                                                    const double* __restrict__ tarea,
                                                    const int* __restrict__ Cnum,
                                                    const int* __restrict__ top_n,
                                                    const float* __restrict__ logits,
                                                    const float* __restrict__ deltas,
                                                    float* __restrict__ out, int B) {
  int b = blockIdx.x, t = threadIdx.x;
  int wave = t >> 6, lane = t & 63;
  int C = Cnum[b];
  const uint32_t* M = maskT + (size_t)b * CH * ROWS * 2;
  const uint2* DT = (const uint2*)diagT + (size_t)b * CH * 64;
  size_t bb = (size_t)b * ROWS;

  __shared__ uint32_t s_f[2][2];
  __shared__ uint32_t kept_lo[POST_K];
  __shared__ uint32_t kept_hi[POST_K];
  __shared__ uint64_t s_kept;
  if (t < 4) ((uint32_t*)s_f)[t] = 0u;

  uint32_t d0 = 0u, d1 = 0u;   // transposed diag words for the current chunk
  if (wave == 0) {
    uint2 td = DT[lane];
    d0 = td.x; d1 = td.y;
  }
  __syncthreads();

  int nkept = 0, nlo = 0, nhi = 0;
  for (int c = 0; c < CH; c++) {
    int base = c * 64;
    if (base >= C) break;
    int cbuf = c & 1;
    if (t == 0) { s_f[cbuf ^ 1][0] = 0u; s_f[cbuf ^ 1][1] = 0u; }

    // phase A: precomputed mask rows (kept_lo)
    uint32_t f0 = 0u, f1 = 0u;
    for (int k2 = t; k2 < nlo; k2 += 256) {
      const uint32_t* rp = M + ((size_t)c * ROWS + kept_lo[k2]) * 2;
      f0 |= rp[0]; f1 |= rp[1];
    }
    // phase B: on-the-fly (kept_hi), BALLOT-FREE — lane j owns column j's bit
    if (nhi > 0) {
      float4 cb4 = tboxf[bb + base + lane];
      float  sca = 0.7f * tareaf[bb + base + lane];
      bool supMine = false;
      for (int k2 = wave; k2 < nhi; k2 += 4) {
        int r = (int)kept_hi[k2];
        float4 r4 = tboxf[bb + r];
        float sra = 0.7f * tareaf[bb + r];
        float iw = fminf(r4.z, cb4.z) - fmaxf(r4.x, cb4.x);
        float ih = fminf(r4.w, cb4.w) - fmaxf(r4.y, cb4.y);
        iw = fmaxf(iw, 0.0f); ih = fmaxf(ih, 0.0f);
        float inter = iw * ih;
        float diff = fmaf(1.7f, inter, -(sra + sca));
        if (diff > IOU_EPS) {
          supMine = true;
        } else if (diff > -IOU_EPS && !supMine) {
          supMine = iou_exact(tbox, tarea, bb + r, bb + base + lane);
        }
      }
      unsigned long long sb = __ballot(supMine);
      f0 |= (uint32_t)sb; f1 |= (uint32_t)(sb >> 32);
    }
#pragma unroll
    for (int off = 32; off > 0; off >>= 1) {
      f0 |= (uint32_t)__shfl_xor((int)f0, off, 64);
      f1 |= (uint32_t)__shfl_xor((int)f1, off, 64);
    }
    if (lane == 0 && (f0 | f1)) {
      atomicOr(&s_f[cbuf][0], f0);
      atomicOr(&s_f[cbuf][1], f1);
    }
    __syncthreads();

    if (wave == 0) {
      uint64_t sup = (uint64_t)s_f[cbuf][0] | ((uint64_t)s_f[cbuf][1] << 32);
      int rem = C - base;
      if (rem < 64) sup |= ~((1ull << rem) - 1ull);
      uint64_t Tj = (uint64_t)d0 | ((uint64_t)d1 << 32);
      int cn = (c + 1 < CH) ? c + 1 : c;
      uint2 tdn = DT[(size_t)cn * 64 + lane];   // prefetch next chunk's T

      // shuffle-free greedy: ballot -> ctz -> per-lane T bit test
      bool aliveMine = !((sup >> lane) & 1ull);
      uint64_t keptMask = 0ull;
      for (;;) {
        unsigned long long bal = __ballot(aliveMine);
        if (!bal) break;
        int i = __builtin_ctzll(bal);
        keptMask |= 1ull << i;
        aliveMine = aliveMine && (lane != i) && !((Tj >> i) & 1ull);
      }
      int allowed = POST_K - nkept;
      int pc = __popcll(keptMask);
      while (pc > allowed) {
        keptMask &= ~(1ull << (63 - __builtin_clzll(keptMask)));
        pc--;
      }
      if (lane == 0) s_kept = keptMask;
      if ((keptMask >> lane) & 1ull) {
        int pfx = __popcll(keptMask & ((1ull << lane) - 1ull));
        int row = base + lane;
        if (c < RC_CH) kept_lo[nlo + pfx] = (uint32_t)row;
        else           kept_hi[nhi + pfx] = (uint32_t)row;
      }
      d0 = tdn.x; d1 = tdn.y;
    }
    __syncthreads();

    int pc = __popcll(s_kept);
    nkept += pc;
    if (c < RC_CH) nlo += pc; else nhi += pc;
    if (nkept >= POST_K) break;
  }

  // ---- fused output: block writes its batch's POST_K rows ----
  __syncthreads();
  int M_out = B * POST_K;
  for (int s2 = t; s2 < POST_K; s2 += 256) {
    float p0 = 0.f, p1 = 0.f, p2 = 0.f, p3 = 0.f;
    float ob = 0.f, d0f = 0.f, d1f = 0.f, d2f = 0.f, d3f = 0.f;
    float bi = -1.0f, okv = 0.0f;
    if (s2 < nkept) {
      int j = (s2 < nlo) ? (int)kept_lo[s2] : (int)kept_hi[s2 - nlo];
      int n = top_n[b * PRE_K + j];
      const double* p = &tbox[(bb + j) * 4];
      p0 = (float)p[0]; p1 = (float)p[1]; p2 = (float)p[2]; p3 = (float)p[3];
      ob = logits[n];
      d0f = deltas[4 * n + 0]; d1f = deltas[4 * n + 1];
      d2f = deltas[4 * n + 2]; d3f = deltas[4 * n + 3];
      bi = (float)b; okv = 1.0f;
    }
    int idx = b * POST_K + s2;
    out[idx * 4 + 0] = p0;
    out[idx * 4 + 1] = p1;
    out[idx * 4 + 2] = p2;
    out[idx * 4 + 3] = p3;
    out[4 * M_out + idx] = bi;
    out[5 * M_out + idx] = ob;
    out[6 * M_out + idx * 4 + 0] = d0f;
    out[6 * M_out + idx * 4 + 1] = d1f;
    out[6 * M_out + idx * 4 + 2] = d2f;
    out[6 * M_out + idx * 4 + 3] = d3f;
    out[10 * M_out + idx] = okv;
  }
}

// ---- launch -----------------------------------------------------------------

extern "C" void kernel_launch(void* const* d_in, const int* in_sizes, int n_in,
                              void* d_out, int out_size, void* d_ws, size_t ws_size,
                              hipStream_t stream) {
  const float* anchors = (const float*)d_in[0];
  const int*   bix     = (const int*)d_in[1];
  const int*   isz     = (const int*)d_in[2];
  const float* logits  = (const float*)d_in[3];
  const float* deltas  = (const float*)d_in[4];
  float* out = (float*)d_out;

  int N = in_sizes[1];
  int B = in_sizes[2] / 2;

  uintptr_t p = (uintptr_t)d_ws;
  double*   tbox   = (double*)p;    p += (size_t)B * ROWS * 4 * sizeof(double);
  double*   tarea  = (double*)p;    p += (size_t)B * ROWS * sizeof(double);
  uint64_t* cand   = (uint64_t*)p;  p += (size_t)B * CAP * sizeof(uint64_t);
  float*    scores = (float*)p;     p += (size_t)N * sizeof(float);
  uint32_t* hist   = (uint32_t*)p;  p += (size_t)B * BINS * sizeof(uint32_t);
  uint32_t* cnt    = (uint32_t*)p;  p += (size_t)B * sizeof(uint32_t);   // adjacent to hist
  uint32_t* prank  = (uint32_t*)p;  p += (size_t)B * JSPLIT * CAP * sizeof(uint32_t);
  int*      top_n    = (int*)p;     p += (size_t)B * PRE_K * sizeof(int);
  int*      Cnum     = (int*)p;      p += (size_t)B * sizeof(int);
  p = (p + 255) & ~(uintptr_t)255;
  uint32_t* maskT    = (uint32_t*)p; p += (size_t)B * CH * ROWS * 2 * sizeof(uint32_t);
  p = (p + 255) & ~(uintptr_t)255;
  uint32_t* diagT    = (uint32_t*)p; p += (size_t)B * CH * 64 * 2 * sizeof(uint32_t);
  // f32 box mirror overlays `scores` (dead after k_compact)
  float4*   tboxf  = (float4*)scores;
  float*    tareaf = (float*)(scores + (size_t)B * ROWS * 4);
  (void)ws_size; (void)n_in; (void)out_size;

  hipMemsetAsync(hist, 0, (size_t)(B * BINS + B) * sizeof(uint32_t), stream);
  k_score<<<(N + 4095) / 4096, 256, 0, stream>>>(anchors, bix, isz, logits, deltas,
                                                 scores, hist, N);
  k_compact<<<(N + 8191) / 8192, 1024, 0, stream>>>(scores, bix, hist, cnt, cand, N);
  k_rank<<<B * 32 * JSPLIT, 256, 0, stream>>>(cand, cnt, prank);
  k_place_gather<<<(B * CAP + 255) / 256, 256, 0, stream>>>(cand, cnt, prank,
                                                            anchors, deltas, isz,
                                                            tbox, tarea, tboxf,
                                                            tareaf, top_n, Cnum, B);
  k_iou_mat<<<B * CH * (RC_CH + 1), 64, 0, stream>>>(tboxf, tareaf, tbox, tarea,
                                                     Cnum, maskT, diagT);
  k_nms_reduce<<<B, 256, 0, stream>>>(maskT, diagT, tboxf, tareaf, tbox, tarea,
                                      Cnum, top_n, logits, deltas, out, B);
}